// Round 1
// baseline (1328.096 us; speedup 1.0000x reference)
//
#include <hip/hip_runtime.h>
#include <hip/hip_bf16.h>

// Problem constants
#define HH 56
#define WWD 56
#define WIN 7
#define SHIFT 3
#define HEADS 8
#define NTOK 49        // WIN*WIN
#define NW 64          // (56/7)^2
#define CDIM 256
#define DH 32          // CDIM/HEADS
#define MROWS 100352   // B*nW*NTOK = 2048*49
#define SCALE_Q 0.17677669529663687f

typedef float floatx4 __attribute__((ext_vector_type(4)));
typedef __bf16 bf16x8 __attribute__((ext_vector_type(8)));

__device__ __forceinline__ float wave_sum(float v) {
#pragma unroll
    for (int m = 1; m < 64; m <<= 1) v += __shfl_xor(v, m);
    return v;
}
__device__ __forceinline__ float wave_max(float v) {
#pragma unroll
    for (int m = 1; m < 64; m <<= 1) v = fmaxf(v, __shfl_xor(v, m));
    return v;
}

// ---------------------------------------------------------------------------
// Weight fp32 -> bf16 conversion (796k elements, trivial)
// dst: [qkv_w 196608][proj_w 65536][fc1_w 262144][fc2_w 262144]
__global__ __launch_bounds__(256) void convert_weights_kernel(
    const float* __restrict__ qkv_w, const float* __restrict__ proj_w,
    const float* __restrict__ fc1_w, const float* __restrict__ fc2_w,
    __hip_bfloat16* __restrict__ dst)
{
    int i = blockIdx.x * 256 + threadIdx.x;
    float v;
    if (i < 196608)       v = qkv_w[i];
    else if (i < 262144)  v = proj_w[i - 196608];
    else if (i < 524288)  v = fc1_w[i - 262144];
    else                  v = fc2_w[i - 524288];
    dst[i] = __float2bfloat16(v);
}

// ---------------------------------------------------------------------------
// LayerNorm; SHIFTED=true also applies roll(-3,-3) + window partition scatter.
// One wave (64 lanes) per token; lane holds 4 channels (float4).
template <bool SHIFTED>
__global__ __launch_bounds__(256) void ln_kernel(
    const float* __restrict__ x, const float* __restrict__ g,
    const float* __restrict__ bb, __hip_bfloat16* __restrict__ out)
{
    const int tok  = blockIdx.x * 4 + (threadIdx.x >> 6);
    const int lane = threadIdx.x & 63;
    const int c    = lane * 4;

    float4 v = *reinterpret_cast<const float4*>(x + (size_t)tok * CDIM + c);
    float s = v.x + v.y + v.z + v.w;
    s = wave_sum(s);
    const float mean = s * (1.0f / 256.0f);
    float d0 = v.x - mean, d1 = v.y - mean, d2 = v.z - mean, d3 = v.w - mean;
    float sq = d0 * d0 + d1 * d1 + d2 * d2 + d3 * d3;
    sq = wave_sum(sq);
    const float rstd = rsqrtf(sq * (1.0f / 256.0f) + 1e-5f);

    float4 gv = *reinterpret_cast<const float4*>(g + c);
    float4 bv = *reinterpret_cast<const float4*>(bb + c);

    union { __hip_bfloat16 h[4]; uint2 u; } pk;
    pk.h[0] = __float2bfloat16(d0 * rstd * gv.x + bv.x);
    pk.h[1] = __float2bfloat16(d1 * rstd * gv.y + bv.y);
    pk.h[2] = __float2bfloat16(d2 * rstd * gv.z + bv.z);
    pk.h[3] = __float2bfloat16(d3 * rstd * gv.w + bv.w);

    size_t oidx;
    if (SHIFTED) {
        int b = tok / 3136;
        int l = tok - b * 3136;
        int h = l / WWD, w = l - (l / WWD) * WWD;
        int hp = h - SHIFT; if (hp < 0) hp += HH;
        int wp = w - SHIFT; if (wp < 0) wp += WWD;
        int bwin = b * NW + (hp / WIN) * 8 + (wp / WIN);
        int n = (hp % WIN) * WIN + (wp % WIN);
        oidx = ((size_t)bwin * NTOK + n) * CDIM + c;
    } else {
        oidx = (size_t)tok * CDIM + c;
    }
    *reinterpret_cast<uint2*>(out + oidx) = pk.u;
}

// ---------------------------------------------------------------------------
// bf16 MFMA GEMM: C[M,N] = A[M,K] * Wt[N,K]^T, fp32 accumulate.
// Block 256 thr = 4 waves, tile 64x64, BK=32; each wave 32x32 (2x2 mfma 16x16x32).
// MODE 0: qkv  -> bf16 out[m*Nn+n], val=(acc+bias)* (n<256 ? SCALE_Q : 1)
// MODE 1: proj -> fp32 scatter window-reverse+roll(+3,+3): out[idx]=aux[idx]+acc+bias
// MODE 2: fc1  -> bf16 out = gelu_exact(acc+bias)
// MODE 3: fc2  -> fp32 out[m*256+n] = aux[m*256+n] + acc + bias
template <int MODE>
__global__ __launch_bounds__(256) void gemm_kernel(
    const __hip_bfloat16* __restrict__ A,
    const __hip_bfloat16* __restrict__ Wt,
    const float* __restrict__ bias,
    void* __restrict__ outv,
    const float* __restrict__ aux,
    int M, int Nn, int K)
{
    __shared__ __hip_bfloat16 As[64 * 40];  // stride 40: 2-way bank conflicts only (free)
    __shared__ __hip_bfloat16 Bs[64 * 40];

    const int t = threadIdx.x;
    const int wave = t >> 6, lane = t & 63;
    const int m0 = blockIdx.y * 64, n0 = blockIdx.x * 64;
    const int wr = (wave >> 1) * 32;   // wave row offset in tile
    const int wc = (wave & 1) * 32;    // wave col offset in tile

    floatx4 acc[2][2] = {};

    const int lrow = t >> 2;           // 0..63
    const int lcol = (t & 3) * 8;      // 0,8,16,24
    const size_t a_base = (size_t)(m0 + lrow) * K + lcol;
    const size_t b_base = (size_t)(n0 + lrow) * K + lcol;

    const int fm = lane & 15;          // fragment row/col within 16
    const int kq = (lane >> 4) * 8;    // fragment k offset

    for (int k0 = 0; k0 < K; k0 += 32) {
        __syncthreads();
        *reinterpret_cast<int4*>(As + lrow * 40 + lcol) =
            *reinterpret_cast<const int4*>(A + a_base + k0);
        *reinterpret_cast<int4*>(Bs + lrow * 40 + lcol) =
            *reinterpret_cast<const int4*>(Wt + b_base + k0);
        __syncthreads();

        bf16x8 a0 = *reinterpret_cast<const bf16x8*>(As + (wr + fm) * 40 + kq);
        bf16x8 a1 = *reinterpret_cast<const bf16x8*>(As + (wr + 16 + fm) * 40 + kq);
        bf16x8 b0 = *reinterpret_cast<const bf16x8*>(Bs + (wc + fm) * 40 + kq);
        bf16x8 b1 = *reinterpret_cast<const bf16x8*>(Bs + (wc + 16 + fm) * 40 + kq);

        acc[0][0] = __builtin_amdgcn_mfma_f32_16x16x32_bf16(a0, b0, acc[0][0], 0, 0, 0);
        acc[0][1] = __builtin_amdgcn_mfma_f32_16x16x32_bf16(a0, b1, acc[0][1], 0, 0, 0);
        acc[1][0] = __builtin_amdgcn_mfma_f32_16x16x32_bf16(a1, b0, acc[1][0], 0, 0, 0);
        acc[1][1] = __builtin_amdgcn_mfma_f32_16x16x32_bf16(a1, b1, acc[1][1], 0, 0, 0);
    }

    // Epilogue. D mapping (verified m89/m91): col = lane&15, row = (lane>>4)*4 + reg.
#pragma unroll
    for (int mi = 0; mi < 2; mi++) {
#pragma unroll
        for (int r = 0; r < 4; r++) {
            const int m_g = m0 + wr + mi * 16 + (lane >> 4) * 4 + r;
            // precompute scatter row index for MODE 1
            size_t row_idx = 0;
            if (MODE == 1) {
                int bwin = m_g / NTOK;
                int ntok = m_g - bwin * NTOK;
                int b = bwin >> 6, wi = bwin & 63;
                int rr = ntok / WIN, cc = ntok - rr * WIN;
                int hp = (wi >> 3) * WIN + rr;
                int wp = (wi & 7) * WIN + cc;
                int h = hp + SHIFT; if (h >= HH) h -= HH;
                int w = wp + SHIFT; if (w >= WWD) w -= WWD;
                row_idx = ((size_t)b * 3136 + h * WWD + w) * CDIM;
            }
#pragma unroll
            for (int ni = 0; ni < 2; ni++) {
                const int n_g = n0 + wc + ni * 16 + (lane & 15);
                float val = acc[mi][ni][r] + bias[n_g];
                if (MODE == 0) {
                    if (n_g < 256) val *= SCALE_Q;
                    reinterpret_cast<__hip_bfloat16*>(outv)[(size_t)m_g * Nn + n_g] =
                        __float2bfloat16(val);
                } else if (MODE == 2) {
                    float gl = 0.5f * val * (1.0f + erff(val * 0.70710678118654752f));
                    reinterpret_cast<__hip_bfloat16*>(outv)[(size_t)m_g * Nn + n_g] =
                        __float2bfloat16(gl);
                } else if (MODE == 3) {
                    size_t idx = (size_t)m_g * CDIM + n_g;
                    reinterpret_cast<float*>(outv)[idx] = aux[idx] + val;
                } else { // MODE 1
                    size_t idx = row_idx + n_g;
                    reinterpret_cast<float*>(outv)[idx] = aux[idx] + val;
                }
            }
        }
    }
}

// ---------------------------------------------------------------------------
// Attention: one block per (window b_, head h). 4 waves, one query row per wave
// per iteration; lane j = key index. Three softmaxes (base / +fg / +bg mask),
// combined p = p0 + p_fg - p_bg, then PV with lane-half split over keys.
__global__ __launch_bounds__(256) void attn_kernel(
    const __hip_bfloat16* __restrict__ qkv,   // (B_,49,768) bf16, q pre-scaled
    const float* __restrict__ rpb_table,      // (169,8)
    const float* __restrict__ attn_mask,      // (64,49,49)
    const float* __restrict__ sal_fg,         // (B_,49,49), key-only: row 0 suffices
    const float* __restrict__ sal_bg,
    __hip_bfloat16* __restrict__ o)           // (B_,49,256), c = h*32+dd
{
    __shared__ float qs[NTOK * 32];
    __shared__ float ks[NTOK * 34];  // stride 34: 2-way conflicts only
    __shared__ float vs[NTOK * 34];
    __shared__ float rpb_l[169];
    __shared__ float prow[4 * 64];

    const int t = threadIdx.x;
    const int b_ = blockIdx.x >> 3, h = blockIdx.x & 7;
    const size_t qkv_base = (size_t)b_ * NTOK * 768 + h * DH;

    for (int idx = t; idx < NTOK * 32; idx += 256) {
        int n = idx >> 5, dd = idx & 31;
        size_t g = qkv_base + (size_t)n * 768 + dd;
        qs[n * 32 + dd] = __bfloat162float(qkv[g]);
        ks[n * 34 + dd] = __bfloat162float(qkv[g + 256]);
        vs[n * 34 + dd] = __bfloat162float(qkv[g + 512]);
    }
    for (int idx = t; idx < 169; idx += 256) rpb_l[idx] = rpb_table[idx * 8 + h];
    __syncthreads();

    const int wave = t >> 6, lane = t & 63;
    const int jr = lane / 7, jc = lane - jr * 7;
    float salfg = 0.f, salbg = 0.f;
    if (lane < NTOK) {
        salfg = sal_fg[(size_t)b_ * (NTOK * NTOK) + lane];
        salbg = sal_bg[(size_t)b_ * (NTOK * NTOK) + lane];
    }
    const float* am_w = attn_mask + (size_t)(b_ & 63) * (NTOK * NTOK);

    for (int r = wave; r < NTOK; r += 4) {
        float s;
        if (lane < NTOK) {
            const float* qr = qs + r * 32;
            const float* kr = ks + lane * 34;
            float acc = 0.f;
#pragma unroll
            for (int kk = 0; kk < 32; kk += 2) {
                float2 qv = *reinterpret_cast<const float2*>(qr + kk);
                float2 kv = *reinterpret_cast<const float2*>(kr + kk);
                acc += qv.x * kv.x + qv.y * kv.y;
            }
            int rr = r / 7, rc = r - rr * 7;
            acc += rpb_l[(rr - jr + 6) * 13 + (rc - jc + 6)];
            acc += am_w[r * NTOK + lane];
            s = acc;
        } else {
            s = -1e30f;
        }
        float l1 = s + salfg, l2 = s + salbg;
        float p = 0.f;
        { float m = wave_max(s);  float e = __expf(s  - m); float ss = wave_sum(e); p += e / ss; }
        { float m = wave_max(l1); float e = __expf(l1 - m); float ss = wave_sum(e); p += e / ss; }
        { float m = wave_max(l2); float e = __expf(l2 - m); float ss = wave_sum(e); p -= e / ss; }
        prow[wave * 64 + lane] = (lane < NTOK) ? p : 0.f;
        // wave-coherent LDS: no barrier needed (single wave writes+reads its segment)

        const int k = lane & 31, half = lane >> 5;
        const float* pw = prow + wave * 64;
        float acc = 0.f;
        const int j0 = half * 25, j1 = j0 + 25 - half;  // half0: 0..24, half1: 25..48
        for (int jj = j0; jj < j1; jj++) acc += pw[jj] * vs[jj * 34 + k];
        float tot = acc + __shfl_xor(acc, 32);
        if (half == 0)
            o[((size_t)b_ * NTOK + r) * CDIM + h * DH + k] = __float2bfloat16(tot);
    }
}

// ---------------------------------------------------------------------------
extern "C" void kernel_launch(void* const* d_in, const int* in_sizes, int n_in,
                              void* d_out, int out_size, void* d_ws, size_t ws_size,
                              hipStream_t stream)
{
    const float* x        = (const float*)d_in[0];
    const float* qkv_w    = (const float*)d_in[1];
    const float* qkv_b    = (const float*)d_in[2];
    const float* rpb_tab  = (const float*)d_in[3];
    const float* proj_w   = (const float*)d_in[4];
    const float* proj_b   = (const float*)d_in[5];
    const float* n1g      = (const float*)d_in[6];
    const float* n1b      = (const float*)d_in[7];
    const float* n2g      = (const float*)d_in[8];
    const float* n2b      = (const float*)d_in[9];
    const float* fc1_w    = (const float*)d_in[10];
    const float* fc1_b    = (const float*)d_in[11];
    const float* fc2_w    = (const float*)d_in[12];
    const float* fc2_b    = (const float*)d_in[13];
    const float* amask    = (const float*)d_in[14];
    const float* sal_fg   = (const float*)d_in[15];
    const float* sal_bg   = (const float*)d_in[16];

    // workspace layout (bytes):
    //  regionA: max(qkv 100352*768*2, fc1out 100352*1024*2) = 205,520,896
    //  regionB: 100352*256*2 = 51,380,224  (xw -> o -> h1n, non-overlapping lifetimes)
    //  x2:      100352*256*4 = 102,760,448
    //  weights bf16: 786432*2 = 1,572,864
    char* ws = (char*)d_ws;
    __hip_bfloat16* regA = (__hip_bfloat16*)ws;
    __hip_bfloat16* regB = (__hip_bfloat16*)(ws + 205520896);
    float*          x2   = (float*)(ws + 205520896 + 51380224);
    __hip_bfloat16* wbf  = (__hip_bfloat16*)(ws + 205520896 + 51380224 + 102760448);
    __hip_bfloat16* wqkv  = wbf;
    __hip_bfloat16* wproj = wbf + 196608;
    __hip_bfloat16* wfc1  = wbf + 262144;
    __hip_bfloat16* wfc2  = wbf + 524288;

    convert_weights_kernel<<<3072, 256, 0, stream>>>(qkv_w, proj_w, fc1_w, fc2_w, wbf);

    // LN1 + shift + window partition -> xw (regB)
    ln_kernel<true><<<MROWS / 4, 256, 0, stream>>>(x, n1g, n1b, regB);

    // qkv GEMM: (100352,256) x (768,256)^T -> regA bf16, q pre-scaled
    gemm_kernel<0><<<dim3(768 / 64, MROWS / 64), 256, 0, stream>>>(
        regB, wqkv, qkv_b, regA, nullptr, MROWS, 768, 256);

    // attention -> o (regB)
    attn_kernel<<<2048 * HEADS, 256, 0, stream>>>(regA, rpb_tab, amask, sal_fg, sal_bg, regB);

    // proj GEMM + window reverse + roll(+3,+3) + residual -> x2 fp32
    gemm_kernel<1><<<dim3(256 / 64, MROWS / 64), 256, 0, stream>>>(
        regB, wproj, proj_b, x2, x, MROWS, 256, 256);

    // LN2 -> h1n (regB)
    ln_kernel<false><<<MROWS / 4, 256, 0, stream>>>(x2, n2g, n2b, regB);

    // fc1 GEMM + GELU -> regA bf16
    gemm_kernel<2><<<dim3(1024 / 64, MROWS / 64), 256, 0, stream>>>(
        regB, wfc1, fc1_b, regA, nullptr, MROWS, 1024, 256);

    // fc2 GEMM + residual(x2) -> d_out fp32
    gemm_kernel<3><<<dim3(256 / 64, MROWS / 64), 256, 0, stream>>>(
        regA, wfc2, fc2_b, d_out, x2, MROWS, 256, 1024);
}

// Round 2
// 959.946 us; speedup vs baseline: 1.3835x; 1.3835x over previous
//
#include <hip/hip_runtime.h>
#include <hip/hip_bf16.h>

// Problem constants
#define HH 56
#define WWD 56
#define WIN 7
#define SHIFT 3
#define HEADS 8
#define NTOK 49        // WIN*WIN
#define NW 64          // (56/7)^2
#define CDIM 256
#define DH 32          // CDIM/HEADS
#define MROWS 100352   // B*nW*NTOK = 2048*49
#define SCALE_Q 0.17677669529663687f

typedef float floatx4 __attribute__((ext_vector_type(4)));
typedef __bf16 bf16x8 __attribute__((ext_vector_type(8)));

__device__ __forceinline__ float wave_sum(float v) {
#pragma unroll
    for (int m = 1; m < 64; m <<= 1) v += __shfl_xor(v, m);
    return v;
}

__device__ __forceinline__ float b2f(unsigned short u) {
    union { unsigned v; float f; } x; x.v = ((unsigned)u) << 16; return x.f;
}

// ---------------------------------------------------------------------------
// Weight fp32 -> bf16 conversion (796k elements, trivial)
__global__ __launch_bounds__(256) void convert_weights_kernel(
    const float* __restrict__ qkv_w, const float* __restrict__ proj_w,
    const float* __restrict__ fc1_w, const float* __restrict__ fc2_w,
    __hip_bfloat16* __restrict__ dst)
{
    int i = blockIdx.x * 256 + threadIdx.x;
    float v;
    if (i < 196608)       v = qkv_w[i];
    else if (i < 262144)  v = proj_w[i - 196608];
    else if (i < 524288)  v = fc1_w[i - 262144];
    else                  v = fc2_w[i - 524288];
    dst[i] = __float2bfloat16(v);
}

// ---------------------------------------------------------------------------
// LayerNorm; SHIFTED=true also applies roll(-3,-3) + window partition scatter.
template <bool SHIFTED>
__global__ __launch_bounds__(256) void ln_kernel(
    const float* __restrict__ x, const float* __restrict__ g,
    const float* __restrict__ bb, __hip_bfloat16* __restrict__ out)
{
    const int tok  = blockIdx.x * 4 + (threadIdx.x >> 6);
    const int lane = threadIdx.x & 63;
    const int c    = lane * 4;

    float4 v = *reinterpret_cast<const float4*>(x + (size_t)tok * CDIM + c);
    float s = v.x + v.y + v.z + v.w;
    s = wave_sum(s);
    const float mean = s * (1.0f / 256.0f);
    float d0 = v.x - mean, d1 = v.y - mean, d2 = v.z - mean, d3 = v.w - mean;
    float sq = d0 * d0 + d1 * d1 + d2 * d2 + d3 * d3;
    sq = wave_sum(sq);
    const float rstd = rsqrtf(sq * (1.0f / 256.0f) + 1e-5f);

    float4 gv = *reinterpret_cast<const float4*>(g + c);
    float4 bv = *reinterpret_cast<const float4*>(bb + c);

    union { __hip_bfloat16 h[4]; uint2 u; } pk;
    pk.h[0] = __float2bfloat16(d0 * rstd * gv.x + bv.x);
    pk.h[1] = __float2bfloat16(d1 * rstd * gv.y + bv.y);
    pk.h[2] = __float2bfloat16(d2 * rstd * gv.z + bv.z);
    pk.h[3] = __float2bfloat16(d3 * rstd * gv.w + bv.w);

    size_t oidx;
    if (SHIFTED) {
        int b = tok / 3136;
        int l = tok - b * 3136;
        int h = l / WWD, w = l - (l / WWD) * WWD;
        int hp = h - SHIFT; if (hp < 0) hp += HH;
        int wp = w - SHIFT; if (wp < 0) wp += WWD;
        int bwin = b * NW + (hp / WIN) * 8 + (wp / WIN);
        int n = (hp % WIN) * WIN + (wp % WIN);
        oidx = ((size_t)bwin * NTOK + n) * CDIM + c;
    } else {
        oidx = (size_t)tok * CDIM + c;
    }
    *reinterpret_cast<uint2*>(out + oidx) = pk.u;
}

// ---------------------------------------------------------------------------
// bf16 MFMA GEMM: C[M,N] = A[M,K] * Wt[N,K]^T, fp32 accumulate.
template <int MODE>
__global__ __launch_bounds__(256) void gemm_kernel(
    const __hip_bfloat16* __restrict__ A,
    const __hip_bfloat16* __restrict__ Wt,
    const float* __restrict__ bias,
    void* __restrict__ outv,
    const float* __restrict__ aux,
    int M, int Nn, int K)
{
    __shared__ __hip_bfloat16 As[64 * 40];
    __shared__ __hip_bfloat16 Bs[64 * 40];

    const int t = threadIdx.x;
    const int wave = t >> 6, lane = t & 63;
    const int m0 = blockIdx.y * 64, n0 = blockIdx.x * 64;
    const int wr = (wave >> 1) * 32;
    const int wc = (wave & 1) * 32;

    floatx4 acc[2][2] = {};

    const int lrow = t >> 2;
    const int lcol = (t & 3) * 8;
    const size_t a_base = (size_t)(m0 + lrow) * K + lcol;
    const size_t b_base = (size_t)(n0 + lrow) * K + lcol;

    const int fm = lane & 15;
    const int kq = (lane >> 4) * 8;

    for (int k0 = 0; k0 < K; k0 += 32) {
        __syncthreads();
        *reinterpret_cast<int4*>(As + lrow * 40 + lcol) =
            *reinterpret_cast<const int4*>(A + a_base + k0);
        *reinterpret_cast<int4*>(Bs + lrow * 40 + lcol) =
            *reinterpret_cast<const int4*>(Wt + b_base + k0);
        __syncthreads();

        bf16x8 a0 = *reinterpret_cast<const bf16x8*>(As + (wr + fm) * 40 + kq);
        bf16x8 a1 = *reinterpret_cast<const bf16x8*>(As + (wr + 16 + fm) * 40 + kq);
        bf16x8 b0 = *reinterpret_cast<const bf16x8*>(Bs + (wc + fm) * 40 + kq);
        bf16x8 b1 = *reinterpret_cast<const bf16x8*>(Bs + (wc + 16 + fm) * 40 + kq);

        acc[0][0] = __builtin_amdgcn_mfma_f32_16x16x32_bf16(a0, b0, acc[0][0], 0, 0, 0);
        acc[0][1] = __builtin_amdgcn_mfma_f32_16x16x32_bf16(a0, b1, acc[0][1], 0, 0, 0);
        acc[1][0] = __builtin_amdgcn_mfma_f32_16x16x32_bf16(a1, b0, acc[1][0], 0, 0, 0);
        acc[1][1] = __builtin_amdgcn_mfma_f32_16x16x32_bf16(a1, b1, acc[1][1], 0, 0, 0);
    }

#pragma unroll
    for (int mi = 0; mi < 2; mi++) {
#pragma unroll
        for (int r = 0; r < 4; r++) {
            const int m_g = m0 + wr + mi * 16 + (lane >> 4) * 4 + r;
            size_t row_idx = 0;
            if (MODE == 1) {
                int bwin = m_g / NTOK;
                int ntok = m_g - bwin * NTOK;
                int b = bwin >> 6, wi = bwin & 63;
                int rr = ntok / WIN, cc = ntok - rr * WIN;
                int hp = (wi >> 3) * WIN + rr;
                int wp = (wi & 7) * WIN + cc;
                int h = hp + SHIFT; if (h >= HH) h -= HH;
                int w = wp + SHIFT; if (w >= WWD) w -= WWD;
                row_idx = ((size_t)b * 3136 + h * WWD + w) * CDIM;
            }
#pragma unroll
            for (int ni = 0; ni < 2; ni++) {
                const int n_g = n0 + wc + ni * 16 + (lane & 15);
                float val = acc[mi][ni][r] + bias[n_g];
                if (MODE == 0) {
                    if (n_g < 256) val *= SCALE_Q;
                    reinterpret_cast<__hip_bfloat16*>(outv)[(size_t)m_g * Nn + n_g] =
                        __float2bfloat16(val);
                } else if (MODE == 2) {
                    float gl = 0.5f * val * (1.0f + erff(val * 0.70710678118654752f));
                    reinterpret_cast<__hip_bfloat16*>(outv)[(size_t)m_g * Nn + n_g] =
                        __float2bfloat16(gl);
                } else if (MODE == 3) {
                    size_t idx = (size_t)m_g * CDIM + n_g;
                    reinterpret_cast<float*>(outv)[idx] = aux[idx] + val;
                } else {
                    size_t idx = row_idx + n_g;
                    reinterpret_cast<float*>(outv)[idx] = aux[idx] + val;
                }
            }
        }
    }
}

// ---------------------------------------------------------------------------
// Attention v2: lane = query row, serial key loop, no cross-lane reductions.
// Block = 4 waves; wave w handles (window b_, head h). K/V fp32 in LDS, read
// broadcast. Shift mask computed from region ids (no LDS/global mask reads).
// Saliency masks are wave-uniform per key -> single ballot bitmask.
__global__ __launch_bounds__(256) void attn_kernel(
    const __hip_bfloat16* __restrict__ qkv,   // (B_,49,768) bf16, q pre-scaled
    const float* __restrict__ rpb_table,      // (169,8)
    const float* __restrict__ sal_fg,         // (B_,49,49): row 0 = key mask
    __hip_bfloat16* __restrict__ o)           // (B_,49,256), c = h*32+d
{
    __shared__ float ks[4 * 1568];   // 49 x 32 fp32 per wave
    __shared__ float vs[4 * 1568];
    __shared__ float rpb_l[4 * 169];

    const int t = threadIdx.x;
    const int wave = t >> 6, lane = t & 63;
    const int b_ = blockIdx.x >> 1;
    const int h = ((blockIdx.x & 1) << 2) | wave;

    float* ksw = ks + wave * 1568;
    float* vsw = vs + wave * 1568;
    float* rpbw = rpb_l + wave * 169;

    const unsigned short* qkv_u = reinterpret_cast<const unsigned short*>(qkv);
    const size_t base = (size_t)b_ * (NTOK * 768) + h * DH;

    // Stage K,V -> fp32 LDS (wave-local, no barrier needed)
#pragma unroll
    for (int it = 0; it < 7; ++it) {
        int q4 = it * 64 + lane;              // quad index 0..391
        if (q4 < 392) {
            int row = q4 >> 3, qq = (q4 & 7) << 2;
            size_t g = base + (size_t)row * 768 + qq;
            ushort4 kk = *reinterpret_cast<const ushort4*>(qkv_u + g + 256);
            ushort4 vv = *reinterpret_cast<const ushort4*>(qkv_u + g + 512);
            float4 kf = { b2f(kk.x), b2f(kk.y), b2f(kk.z), b2f(kk.w) };
            float4 vf = { b2f(vv.x), b2f(vv.y), b2f(vv.z), b2f(vv.w) };
            *reinterpret_cast<float4*>(ksw + row * 32 + qq) = kf;
            *reinterpret_cast<float4*>(vsw + row * 32 + qq) = vf;
        }
    }
#pragma unroll
    for (int it = 0; it < 3; ++it) {
        int idx = it * 64 + lane;
        if (idx < 169) rpbw[idx] = rpb_table[idx * 8 + h];
    }

    // q row for this lane (registers)
    const int r = (lane < NTOK) ? lane : 48;
    float qf[32];
#pragma unroll
    for (int cc = 0; cc < 8; ++cc) {
        ushort4 qq = *reinterpret_cast<const ushort4*>(
            qkv_u + base + (size_t)r * 768 + cc * 4);
        qf[cc * 4 + 0] = b2f(qq.x);
        qf[cc * 4 + 1] = b2f(qq.y);
        qf[cc * 4 + 2] = b2f(qq.z);
        qf[cc * 4 + 3] = b2f(qq.w);
    }

    // saliency key bitmask (wave-uniform)
    float sfv = (lane < NTOK) ? sal_fg[(size_t)b_ * (NTOK * NTOK) + lane] : -100.f;
    const unsigned long long fgmask = __ballot(sfv == 0.0f);

    // region id for shift mask (replaces attn_mask reads)
    const int wr_ = (b_ & 63) >> 3, wc_ = (b_ & 63) & 7;
    const int rr = r / 7, rc = r - (r / 7) * 7;
    const int rreg = ((wr_ == 7) ? ((rr < 4) ? 1 : 2) : 0) * 3
                   + ((wc_ == 7) ? ((rc < 4) ? 1 : 2) : 0);
    const int rpb_base = rr * 13 + rc;

    // ---- pass 1a: logits into registers + running maxes
    float sreg[49];
    float m0 = -1e30f, m1 = -1e30f, m2 = -1e30f;
#pragma unroll
    for (int j = 0; j < 49; ++j) {
        const int jr = j / 7, jc = j - (j / 7) * 7;   // compile-time
        float2 acc = { 0.f, 0.f };
#pragma unroll
        for (int d4 = 0; d4 < 8; ++d4) {
            float4 kv = *reinterpret_cast<const float4*>(ksw + j * 32 + d4 * 4);
            acc.x = fmaf(qf[d4 * 4 + 0], kv.x, acc.x);
            acc.y = fmaf(qf[d4 * 4 + 1], kv.y, acc.y);
            acc.x = fmaf(qf[d4 * 4 + 2], kv.z, acc.x);
            acc.y = fmaf(qf[d4 * 4 + 3], kv.w, acc.y);
        }
        float s = acc.x + acc.y;
        s += rpbw[rpb_base + (6 - jr) * 13 + (6 - jc)];
        const int jreg = ((wr_ == 7) ? ((jr < 4) ? 1 : 2) : 0) * 3
                       + ((wc_ == 7) ? ((jc < 4) ? 1 : 2) : 0);
        s += (rreg == jreg) ? 0.f : -100.f;
        const float sf = ((fgmask >> j) & 1ULL) ? 0.f : -100.f;
        sreg[j] = s;
        m0 = fmaxf(m0, s);
        m1 = fmaxf(m1, s + sf);
        m2 = fmaxf(m2, s - 100.f - sf);
    }

    // ---- pass 1b: denominators
    float S0 = 0.f, S1 = 0.f, S2 = 0.f;
#pragma unroll
    for (int j = 0; j < 49; ++j) {
        const float sf = ((fgmask >> j) & 1ULL) ? 0.f : -100.f;
        S0 += __expf(sreg[j] - m0);
        S1 += __expf(sreg[j] + sf - m1);
        S2 += __expf(sreg[j] - 100.f - sf - m2);
    }
    const float r0 = 1.f / S0, r1 = 1.f / S1, r2 = 1.f / S2;

    // ---- pass 2: combined probabilities + PV
    float2 oacc[16];
#pragma unroll
    for (int d = 0; d < 16; ++d) { oacc[d].x = 0.f; oacc[d].y = 0.f; }
#pragma unroll
    for (int j = 0; j < 49; ++j) {
        const float sf = ((fgmask >> j) & 1ULL) ? 0.f : -100.f;
        const float p = __expf(sreg[j] - m0) * r0
                      + __expf(sreg[j] + sf - m1) * r1
                      - __expf(sreg[j] - 100.f - sf - m2) * r2;
#pragma unroll
        for (int d4 = 0; d4 < 8; ++d4) {
            float4 vv = *reinterpret_cast<const float4*>(vsw + j * 32 + d4 * 4);
            oacc[d4 * 2 + 0].x = fmaf(p, vv.x, oacc[d4 * 2 + 0].x);
            oacc[d4 * 2 + 0].y = fmaf(p, vv.y, oacc[d4 * 2 + 0].y);
            oacc[d4 * 2 + 1].x = fmaf(p, vv.z, oacc[d4 * 2 + 1].x);
            oacc[d4 * 2 + 1].y = fmaf(p, vv.w, oacc[d4 * 2 + 1].y);
        }
    }

    if (lane < NTOK) {
        __hip_bfloat16 ob[32];
#pragma unroll
        for (int d = 0; d < 16; ++d) {
            ob[2 * d]     = __float2bfloat16(oacc[d].x);
            ob[2 * d + 1] = __float2bfloat16(oacc[d].y);
        }
        __hip_bfloat16* op = o + ((size_t)b_ * NTOK + lane) * CDIM + h * DH;
#pragma unroll
        for (int ii = 0; ii < 4; ++ii)
            reinterpret_cast<int4*>(op)[ii] = reinterpret_cast<const int4*>(ob)[ii];
    }
}

// ---------------------------------------------------------------------------
extern "C" void kernel_launch(void* const* d_in, const int* in_sizes, int n_in,
                              void* d_out, int out_size, void* d_ws, size_t ws_size,
                              hipStream_t stream)
{
    const float* x        = (const float*)d_in[0];
    const float* qkv_w    = (const float*)d_in[1];
    const float* qkv_b    = (const float*)d_in[2];
    const float* rpb_tab  = (const float*)d_in[3];
    const float* proj_w   = (const float*)d_in[4];
    const float* proj_b   = (const float*)d_in[5];
    const float* n1g      = (const float*)d_in[6];
    const float* n1b      = (const float*)d_in[7];
    const float* n2g      = (const float*)d_in[8];
    const float* n2b      = (const float*)d_in[9];
    const float* fc1_w    = (const float*)d_in[10];
    const float* fc1_b    = (const float*)d_in[11];
    const float* fc2_w    = (const float*)d_in[12];
    const float* fc2_b    = (const float*)d_in[13];
    const float* sal_fg   = (const float*)d_in[15];

    char* ws = (char*)d_ws;
    __hip_bfloat16* regA = (__hip_bfloat16*)ws;
    __hip_bfloat16* regB = (__hip_bfloat16*)(ws + 205520896);
    float*          x2   = (float*)(ws + 205520896 + 51380224);
    __hip_bfloat16* wbf  = (__hip_bfloat16*)(ws + 205520896 + 51380224 + 102760448);
    __hip_bfloat16* wqkv  = wbf;
    __hip_bfloat16* wproj = wbf + 196608;
    __hip_bfloat16* wfc1  = wbf + 262144;
    __hip_bfloat16* wfc2  = wbf + 524288;

    convert_weights_kernel<<<3072, 256, 0, stream>>>(qkv_w, proj_w, fc1_w, fc2_w, wbf);

    ln_kernel<true><<<MROWS / 4, 256, 0, stream>>>(x, n1g, n1b, regB);

    gemm_kernel<0><<<dim3(768 / 64, MROWS / 64), 256, 0, stream>>>(
        regB, wqkv, qkv_b, regA, nullptr, MROWS, 768, 256);

    attn_kernel<<<2048 * 2, 256, 0, stream>>>(regA, rpb_tab, sal_fg, regB);

    gemm_kernel<1><<<dim3(256 / 64, MROWS / 64), 256, 0, stream>>>(
        regB, wproj, proj_b, x2, x, MROWS, 256, 256);

    ln_kernel<false><<<MROWS / 4, 256, 0, stream>>>(x2, n2g, n2b, regB);

    gemm_kernel<2><<<dim3(1024 / 64, MROWS / 64), 256, 0, stream>>>(
        regB, wfc1, fc1_b, regA, nullptr, MROWS, 1024, 256);

    gemm_kernel<3><<<dim3(256 / 64, MROWS / 64), 256, 0, stream>>>(
        regA, wfc2, fc2_b, d_out, x2, MROWS, 256, 1024);
}